// Round 8
// baseline (317.585 us; speedup 1.0000x reference)
//
#include <hip/hip_runtime.h>
#include <hip/hip_bf16.h>
#include <cmath>

#define BS 8
#define SEQ 16384
#define D 128
#define NH 8
#define HD 16
#define EPS_ 1e-5f

#define CH 64                       // tokens per chunk
#define NCHK_A 2                    // chunks per passA block -> 1024 blocks
#define BPB_A (SEQ/(CH*NCHK_A))     // 128
#define CPB_B 2                     // chunks per passB block -> 1024 blocks
#define BPB_B (SEQ/(CH*CPB_B))      // 128
#define CPBATCH (SEQ/CH)            // 256 chunks per batch

typedef __attribute__((ext_vector_type(8))) short bf16x8;
typedef __attribute__((ext_vector_type(4))) float f32x4;
typedef __attribute__((ext_vector_type(4))) unsigned int u32x4;
typedef __attribute__((ext_vector_type(2))) unsigned int u32x2;

#define MFMA16(a,b,c) __builtin_amdgcn_mfma_f32_16x16x32_bf16(a,b,c,0,0,0)

__device__ __forceinline__ unsigned short bf16rn(float x){
    union { __hip_bfloat16 h; unsigned short u; } v;
    v.h = __float2bfloat16(x);
    return v.u;
}
__device__ __forceinline__ float bf16tof(unsigned int u16){
    union { unsigned int u; float f; } v;
    v.u = u16 << 16;
    return v.f;
}
__device__ __forceinline__ unsigned int cvt2(float a, float b){
    union { __hip_bfloat162 h; unsigned int u; } v;
    v.h = __float22bfloat162_rn(make_float2(a, b));
    return v.u;
}
// natural [64 tok][128 col] bf16 LDS; XOR-swizzle, 16B granule
__device__ __forceinline__ int swzQ(int tok, int col){ return (tok*128 + col) ^ ((tok&7)<<3); }

// Build k-major MFMA frag (32 toks = C-tiles {e0,e1}) from C-layout registers.
// Source lane s=(tok16>>2)*16+d holds (col d, toks tok16&3 per reg pair).
// Target lane l (g=l>>4, d=l&15) wants toks (l>>4)*8..+8 of tile (l>=32 ? e1 : e0).
// BUG FIX (r7): tile select must use the TARGET's hiT, so fetch BOTH tiles'
// pairs through the shuffle and v_cndmask at the target.
__device__ __forceinline__ bf16x8 exch(unsigned e0p0, unsigned e0p1,
                                       unsigned e1p0, unsigned e1p1,
                                       int srcA, int srcB, bool hiT){
    unsigned a0 = (unsigned)__shfl((int)e0p0, srcA, 64);
    unsigned a1 = (unsigned)__shfl((int)e0p1, srcA, 64);
    unsigned a2 = (unsigned)__shfl((int)e0p0, srcB, 64);
    unsigned a3 = (unsigned)__shfl((int)e0p1, srcB, 64);
    unsigned b0 = (unsigned)__shfl((int)e1p0, srcA, 64);
    unsigned b1 = (unsigned)__shfl((int)e1p1, srcA, 64);
    unsigned b2 = (unsigned)__shfl((int)e1p0, srcB, 64);
    unsigned b3 = (unsigned)__shfl((int)e1p1, srcB, 64);
    union { u32x4 u; bf16x8 h; } r;
    r.u.x = hiT ? b0 : a0;
    r.u.y = hiT ? b1 : a1;
    r.u.z = hiT ? b2 : a2;
    r.u.w = hiT ? b3 : a3;
    return r.h;
}

// ---------------------------------------------------------------------------
// Weight pre-pack: WB (k|v B-frags, 16 nt tiles), WqA (Wq A-frags). 24 blocks.
// ---------------------------------------------------------------------------
__global__ __launch_bounds__(256) void packW(
    const float* __restrict__ Wk, const float* __restrict__ Wv,
    const float* __restrict__ Wq,
    short* __restrict__ WB, short* __restrict__ WqA)
{
    int e = blockIdx.x * 256 + threadIdx.x;     // 0..6143
    short v8[8];
    if (e < 4096) {
        int nt = e >> 8, kt = (e >> 6) & 3, l = e & 63;
        int col = nt * 16 + (l & 15);
        const float* W = (col < 128) ? Wk : Wv;
        int cc = col & 127;
#pragma unroll
        for (int j = 0; j < 8; ++j)
            v8[j] = (short)bf16rn(W[(kt*32 + (l>>4)*8 + j)*D + cc]);
        u32x4 p = u32x4{ (unsigned)(unsigned short)v8[0] | ((unsigned)(unsigned short)v8[1]<<16),
                         (unsigned)(unsigned short)v8[2] | ((unsigned)(unsigned short)v8[3]<<16),
                         (unsigned)(unsigned short)v8[4] | ((unsigned)(unsigned short)v8[5]<<16),
                         (unsigned)(unsigned short)v8[6] | ((unsigned)(unsigned short)v8[7]<<16) };
        *(u32x4*)&WB[((nt*4 + kt)*64 + l)*8] = p;
    } else {
        int e2 = e - 4096;                      // 0..2047
        int mt = e2 >> 8, kt = (e2 >> 6) & 3, l = e2 & 63;
        int m = mt*16 + (l & 15);
#pragma unroll
        for (int j = 0; j < 8; ++j)
            v8[j] = (short)bf16rn(Wq[(kt*32 + (l>>4)*8 + j)*D + m]);
        u32x4 p = u32x4{ (unsigned)(unsigned short)v8[0] | ((unsigned)(unsigned short)v8[1]<<16),
                         (unsigned)(unsigned short)v8[2] | ((unsigned)(unsigned short)v8[3]<<16),
                         (unsigned)(unsigned short)v8[4] | ((unsigned)(unsigned short)v8[5]<<16),
                         (unsigned)(unsigned short)v8[6] | ((unsigned)(unsigned short)v8[7]<<16) };
        *(u32x4*)&WqA[((mt*4 + kt)*64 + l)*8] = p;
    }
}

// ---------------------------------------------------------------------------
// Pass A: k,v,q projections (shared Q frags); phi; KV via register-shuffle
// frag build + MFMA; Ksum via VALU. LDS = 16 KB (Qlds only), no TL.
// Wave w owns heads {2w, 2w+1}: its k-cols, v-cols, q-cols.
// ---------------------------------------------------------------------------
__global__ __launch_bounds__(256, 3) void passA(
    const float* __restrict__ Q,
    const float* __restrict__ bk, const float* __restrict__ bv,
    const float* __restrict__ bq,
    const short* __restrict__ WB, const short* __restrict__ WqA,
    float* __restrict__ KV, float* __restrict__ Ksum,
    u32x2* __restrict__ phiq)
{
    __shared__ __align__(16) short Qlds[64*128];   // 16 KB

    const int t = threadIdx.x;
    const int w = t >> 6, l = t & 63;
    const int g = l >> 4, d = l & 15;
    const int b  = blockIdx.x / BPB_A;
    const int bb = blockIdx.x % BPB_A;
    const long base = (long)b * SEQ + (long)bb * (CH * NCHK_A);

    // weight frags: wave's 2 head-tiles of Wk, Wv (B-frags) and Wq (A-frags)
    bf16x8 wbk[2][4], wbv[2][4], wqa[2][4];
#pragma unroll
    for (int tl = 0; tl < 2; ++tl)
#pragma unroll
        for (int kt = 0; kt < 4; ++kt) {
            wbk[tl][kt] = *(const bf16x8*)&WB [(((    2*w+tl)*4 + kt)*64 + l)*8];
            wbv[tl][kt] = *(const bf16x8*)&WB [(((8 + 2*w+tl)*4 + kt)*64 + l)*8];
            wqa[tl][kt] = *(const bf16x8*)&WqA[(((    2*w+tl)*4 + kt)*64 + l)*8];
        }

    float bky[2], bvy[2], bqy[2][4];
#pragma unroll
    for (int tl = 0; tl < 2; ++tl) {
        bky[tl] = bk[(2*w+tl)*16 + d];
        bvy[tl] = bv[(2*w+tl)*16 + d];
#pragma unroll
        for (int r = 0; r < 4; ++r)
            bqy[tl][r] = bq[(2*w+tl)*16 + g*4 + r];
    }

    const int  srcA = ((g & 1) * 2) * 16 + d;
    const int  srcB = srcA + 16;
    const bool hiT  = (l >= 32);

    const f32x4 z4 = {0.f, 0.f, 0.f, 0.f};
    f32x4 kvacc[2] = {z4, z4};
    float ksacc[2] = {0.f, 0.f};

    for (int c = 0; c < NCHK_A; ++c) {
        const long tok0 = base + (long)c * CH;
        const int chunkG = b*CPBATCH + bb*NCHK_A + c;

        __syncthreads();  // protect Qlds from previous chunk's readers
        // --- stage Q chunk -> bf16 LDS ---
#pragma unroll
        for (int i = 0; i < 4; ++i) {
            int lin = i*256 + t;
            int row = lin >> 4;
            int c0  = (lin & 15) * 8;
            const float4* gp = (const float4*)&Q[(tok0 + row)*D + c0];
            float4 a = gp[0], a2 = gp[1];
            u32x4 p = u32x4{cvt2(a.x,a.y), cvt2(a.z,a.w), cvt2(a2.x,a2.y), cvt2(a2.z,a2.w)};
            *(u32x4*)&Qlds[swzQ(row, c0)] = p;
        }
        __syncthreads();

        unsigned pkk[4][2][2], pkv[4][2][2];   // [tok-tile][head-tile][pair]
#pragma unroll
        for (int mt = 0; mt < 4; ++mt) {
            bf16x8 qf[4];
#pragma unroll
            for (int kt = 0; kt < 4; ++kt)
                qf[kt] = *(bf16x8*)&Qlds[swzQ(mt*16 + d, kt*32 + g*8)];
#pragma unroll
            for (int tl = 0; tl < 2; ++tl) {
                // k-proj (C[tok][col]), phi, round, Ksum partial
                f32x4 ak = f32x4{bky[tl], bky[tl], bky[tl], bky[tl]};
#pragma unroll
                for (int kt = 0; kt < 4; ++kt)
                    ak = MFMA16(qf[kt], wbk[tl][kt], ak);
                unsigned sk[4];
#pragma unroll
                for (int r = 0; r < 4; ++r) {
                    float x = ak[r];
                    x = (x > 0.f) ? (x + 1.f) : __expf(x);
                    sk[r] = bf16rn(x);
                    ksacc[tl] += bf16tof(sk[r]);
                }
                pkk[mt][tl][0] = sk[0] | (sk[1] << 16);
                pkk[mt][tl][1] = sk[2] | (sk[3] << 16);
                // v-proj
                f32x4 av = f32x4{bvy[tl], bvy[tl], bvy[tl], bvy[tl]};
#pragma unroll
                for (int kt = 0; kt < 4; ++kt)
                    av = MFMA16(qf[kt], wbv[tl][kt], av);
                pkv[mt][tl][0] = cvt2(av[0], av[1]);
                pkv[mt][tl][1] = cvt2(av[2], av[3]);
                // q-proj (swapped, C[qcol][tok]), phi, store frag to ws
                f32x4 qa = f32x4{bqy[tl][0], bqy[tl][1], bqy[tl][2], bqy[tl][3]};
#pragma unroll
                for (int kt = 0; kt < 4; ++kt)
                    qa = MFMA16(wqa[tl][kt], qf[kt], qa);
                unsigned sq[4];
#pragma unroll
                for (int r = 0; r < 4; ++r) {
                    float x = qa[r];
                    x = (x > 0.f) ? (x + 1.f) : __expf(x);
                    sq[r] = bf16rn(x);
                }
                phiq[((chunkG*8 + (2*w+tl))*4 + mt)*64 + l] =
                    u32x2{ sq[0] | (sq[1]<<16), sq[2] | (sq[3]<<16) };
            }
        }

        // --- KV accumulation: register-shuffle frag build + MFMA ---
#pragma unroll
        for (int hh = 0; hh < 2; ++hh)
#pragma unroll
            for (int kt2 = 0; kt2 < 2; ++kt2) {
                bf16x8 Ak = exch(pkk[2*kt2][hh][0], pkk[2*kt2][hh][1],
                                 pkk[2*kt2+1][hh][0], pkk[2*kt2+1][hh][1],
                                 srcA, srcB, hiT);
                bf16x8 Bv = exch(pkv[2*kt2][hh][0], pkv[2*kt2][hh][1],
                                 pkv[2*kt2+1][hh][0], pkv[2*kt2+1][hh][1],
                                 srcA, srcB, hiT);
                kvacc[hh] = MFMA16(Ak, Bv, kvacc[hh]);
            }
    }

    // epilogue: KV atomics (D layout: row d = g*4+r, col m = d-lane)
#pragma unroll
    for (int hh = 0; hh < 2; ++hh) {
#pragma unroll
        for (int r = 0; r < 4; ++r)
            atomicAdd(&KV[((b*NH + 2*w+hh)*HD + g*4 + r)*HD + d], kvacc[hh][r]);
        float s = ksacc[hh];
        s += __shfl_xor(s, 16, 64);
        s += __shfl_xor(s, 32, 64);
        if (l < 16)
            atomicAdd(&Ksum[(b*NH + 2*w+hh)*HD + l], s);
    }
}

// ---------------------------------------------------------------------------
// packW2: W2[b] = KV[b] . Wo, stored as A-frags. 64 blocks = (b, h).
// ---------------------------------------------------------------------------
__global__ __launch_bounds__(256) void packW2(
    const float* __restrict__ Wo, const float* __restrict__ KV,
    short* __restrict__ W2A)
{
    __shared__ float KVs[HD*HD];
    const int b = blockIdx.x >> 3, h = blockIdx.x & 7, t = threadIdx.x;
    KVs[t] = KV[(b*NH + h)*HD*HD + t];
    __syncthreads();

    const int oc = t & 127, dg = t >> 7;    // dg in {0,1}: qd rows h*16+dg*8..+8
    float acc[8];
#pragma unroll
    for (int j = 0; j < 8; ++j) acc[j] = 0.f;
    for (int m = 0; m < 16; ++m) {
        float wv = Wo[(h*16 + m)*D + oc];
#pragma unroll
        for (int j = 0; j < 8; ++j)
            acc[j] += KVs[(dg*8 + j)*16 + m] * wv;
    }
    // frag slot: mt = oc>>4, kt = h>>1, lane = ((h&1)*2+dg)*16 + (oc&15)
    unsigned p0 = (unsigned)bf16rn(acc[0]) | ((unsigned)bf16rn(acc[1])<<16);
    unsigned p1 = (unsigned)bf16rn(acc[2]) | ((unsigned)bf16rn(acc[3])<<16);
    unsigned p2 = (unsigned)bf16rn(acc[4]) | ((unsigned)bf16rn(acc[5])<<16);
    unsigned p3 = (unsigned)bf16rn(acc[6]) | ((unsigned)bf16rn(acc[7])<<16);
    int lane = ((h & 1)*2 + dg)*16 + (oc & 15);
    *(u32x4*)&W2A[(((b*8 + (oc>>4))*4 + (h>>1))*64 + lane)*8] = u32x4{p0,p1,p2,p3};
}

// ---------------------------------------------------------------------------
// Pass B: Z from phiq frags (1 shfl), scale, out = phiq~ @ W2 + bo.
// Zero LDS. 1024 blocks x 128 tokens.
// ---------------------------------------------------------------------------
__global__ __launch_bounds__(256, 4) void passB(
    const float* __restrict__ bo,
    const short* __restrict__ W2A, const float* __restrict__ Ksum,
    const u32x2* __restrict__ phiq,
    float* __restrict__ out)
{
    const int t = threadIdx.x;
    const int w = t >> 6, l = t & 63;
    const int b  = blockIdx.x / BPB_B;
    const int cb = blockIdx.x % BPB_B;

    bf16x8 w2[2][4];
#pragma unroll
    for (int m = 0; m < 2; ++m)
#pragma unroll
        for (int kt = 0; kt < 4; ++kt)
            w2[m][kt] = *(const bf16x8*)&W2A[(((b*8 + (w*2+m))*4 + kt)*64 + l)*8];

    float bov[2][4];
#pragma unroll
    for (int m = 0; m < 2; ++m)
#pragma unroll
        for (int r = 0; r < 4; ++r)
            bov[m][r] = bo[(w*2+m)*16 + (l>>4)*4 + r];

    float Ks[4][8];
#pragma unroll
    for (int kt = 0; kt < 4; ++kt) {
        const float* kp = &Ksum[b*D + kt*32 + (l>>4)*8];
        f32x4 k0 = *(const f32x4*)kp;
        f32x4 k1 = *(const f32x4*)(kp + 4);
#pragma unroll
        for (int j = 0; j < 4; ++j) { Ks[kt][j] = k0[j]; Ks[kt][4+j] = k1[j]; }
    }

    const int lnb   = ((l>>4)&1)*32 + (l&15);   // source lane for j0..3
    const int qhalf = (l >= 32) ? 1 : 0;        // which qt of the kt pair

    for (int c = 0; c < CPB_B; ++c) {
        const int chunkG = b*CPBATCH + cb*CPB_B + c;
        const long tokbase = (long)b*SEQ + (long)(cb*CPB_B + c)*CH;

#pragma unroll
        for (int nt = 0; nt < 4; ++nt) {
            bf16x8 bfrag[4];
#pragma unroll
            for (int kt = 0; kt < 4; ++kt) {
                const int slotbase = ((chunkG*8 + 2*kt + qhalf)*4 + nt)*64;
                u32x2 fa = phiq[slotbase + lnb];
                u32x2 fb = phiq[slotbase + lnb + 16];
                float v0 = bf16tof(fa.x & 0xffffu), v1 = bf16tof(fa.x >> 16);
                float v2 = bf16tof(fa.y & 0xffffu), v3 = bf16tof(fa.y >> 16);
                float v4 = bf16tof(fb.x & 0xffffu), v5 = bf16tof(fb.x >> 16);
                float v6 = bf16tof(fb.y & 0xffffu), v7 = bf16tof(fb.y >> 16);
                float s = v0*Ks[kt][0] + v1*Ks[kt][1] + v2*Ks[kt][2] + v3*Ks[kt][3]
                        + v4*Ks[kt][4] + v5*Ks[kt][5] + v6*Ks[kt][6] + v7*Ks[kt][7];
                s += __shfl_xor(s, 16, 64);        // combine the two 8-dim halves
                float z = 1.f / (s + EPS_);
                union { u32x4 u; bf16x8 h; } pk;
                pk.u = u32x4{ cvt2(v0*z, v1*z), cvt2(v2*z, v3*z),
                              cvt2(v4*z, v5*z), cvt2(v6*z, v7*z) };
                bfrag[kt] = pk.h;
            }
#pragma unroll
            for (int m = 0; m < 2; ++m) {
                f32x4 acc = f32x4{bov[m][0], bov[m][1], bov[m][2], bov[m][3]};
#pragma unroll
                for (int kt = 0; kt < 4; ++kt)
                    acc = MFMA16(w2[m][kt], bfrag[kt], acc);
                long tok = tokbase + nt*16 + (l & 15);
                *(float4*)&out[tok*D + (w*2+m)*16 + (l>>4)*4] =
                    float4{acc[0], acc[1], acc[2], acc[3]};
            }
        }
    }
}

extern "C" void kernel_launch(void* const* d_in, const int* in_sizes, int n_in,
                              void* d_out, int out_size, void* d_ws, size_t ws_size,
                              hipStream_t stream) {
    (void)in_sizes; (void)n_in; (void)out_size; (void)ws_size;
    const float* Q  = (const float*)d_in[0];
    const float* Wq = (const float*)d_in[1];
    const float* bq = (const float*)d_in[2];
    const float* Wk = (const float*)d_in[3];
    const float* bk = (const float*)d_in[4];
    const float* Wv = (const float*)d_in[5];
    const float* bv = (const float*)d_in[6];
    const float* Wo = (const float*)d_in[7];
    const float* bo = (const float*)d_in[8];
    float* out = (float*)d_out;

    // ws carve (bytes): KV 64K | Ksum 4K | WB 64K | WqA 32K | W2A 256K | phiq 32M
    char* p = (char*)d_ws;
    float* KV    = (float*)p;                 p += 16384 * sizeof(float);
    float* Ksum  = (float*)p;                 p += 1024  * sizeof(float);
    short* WB    = (short*)p;                 p += 32768 * sizeof(short);
    short* WqA   = (short*)p;                 p += 16384 * sizeof(short);
    short* W2A   = (short*)p;                 p += 131072 * sizeof(short);
    u32x2* phiq  = (u32x2*)p;                 // 2048*8*4*64 slots * 8B = 32 MB

    hipMemsetAsync(d_ws, 0, (16384 + 1024)*sizeof(float), stream);
    packW <<<dim3(24),        dim3(256), 0, stream>>>(Wk, Wv, Wq, WB, WqA);
    passA <<<dim3(BS*BPB_A),  dim3(256), 0, stream>>>(Q, bk, bv, bq, WB, WqA, KV, Ksum, phiq);
    packW2<<<dim3(BS*NH),     dim3(256), 0, stream>>>(Wo, KV, W2A);
    passB <<<dim3(BS*BPB_B),  dim3(256), 0, stream>>>(bo, W2A, Ksum, phiq, out);
}